// Round 7
// baseline (237.219 us; speedup 1.0000x reference)
//
#include <hip/hip_runtime.h>
#include <hip/hip_bf16.h>
#include <stdint.h>

#define NN 4096
#define KIN 512
#define HH 8
#define HF 256
#define LOG2E 1.4426950408889634f

typedef float f32x4 __attribute__((ext_vector_type(4)));
typedef short s16x8 __attribute__((ext_vector_type(8)));
typedef __bf16 bf16x8 __attribute__((ext_vector_type(8)));
typedef unsigned int u32x4 __attribute__((ext_vector_type(4)));

#if defined(__has_builtin)
#if __has_builtin(__builtin_amdgcn_exp2f)
#define EXP2(x) __builtin_amdgcn_exp2f(x)
#else
#define EXP2(x) exp2f(x)
#endif
#else
#define EXP2(x) exp2f(x)
#endif

// ---------------------------------------------------------------------------
// k_pack: adjacency (any of 4 storage modes, sniffed per-block) -> 1-bit
// bitmask bm[4096][128] u32 (2 MB). One HBM-rate pass; everything downstream
// reads 32x less.
// ---------------------------------------------------------------------------
__global__ __launch_bounds__(256) void k_pack(const void* __restrict__ adjv,
                                              uint32_t* __restrict__ bm) {
  __shared__ int smode;
  if (threadIdx.x == 0) {
    const uint32_t* aw = (const uint32_t*)adjv;
    const uint32_t w0 = aw[0];
    int f;
    if (w0 == 0x3F800000u) f = 2;                 // fp32 0/1
    else if ((w0 & 0xFFFFu) == 0x3F80u) f = 3;    // bf16 0/1
    else {
      int alli = 1;
      for (int k = 0; k < 64; ++k)
        if (aw[k] > 1u) { alli = 0; break; }
      f = alli ? 1 : 0;                           // int32 : uint8
    }
    smode = f;
  }
  __syncthreads();
  const int mode = smode;
  const int t = blockIdx.x * 256 + threadIdx.x;   // 0..524287
  const int r = t >> 7, w = t & 127;              // row, 32-elem word
  uint32_t word = 0;
  if (mode == 0) {
    const u32x4* p = (const u32x4*)((const uint8_t*)adjv + ((size_t)r << 12) + w * 32);
#pragma unroll
    for (int k = 0; k < 2; ++k) {
      const u32x4 v = __builtin_nontemporal_load(&p[k]);
#pragma unroll
      for (int q = 0; q < 4; ++q)
#pragma unroll
        for (int b = 0; b < 4; ++b)
          if ((v[q] >> (8 * b)) & 0xFFu) word |= (1u << (k * 16 + q * 4 + b));
    }
  } else if (mode == 3) {
    const u32x4* p = (const u32x4*)((const uint16_t*)adjv + ((size_t)r << 12) + w * 32);
#pragma unroll
    for (int k = 0; k < 4; ++k) {
      const u32x4 v = __builtin_nontemporal_load(&p[k]);
#pragma unroll
      for (int q = 0; q < 4; ++q) {
        if (v[q] & 0xFFFFu) word |= (1u << (k * 8 + q * 2 + 0));
        if (v[q] >> 16)     word |= (1u << (k * 8 + q * 2 + 1));
      }
    }
  } else {
    const u32x4* p = (const u32x4*)((const uint32_t*)adjv + ((size_t)r << 12) + w * 32);
#pragma unroll
    for (int k = 0; k < 8; ++k) {
      const u32x4 v = __builtin_nontemporal_load(&p[k]);
#pragma unroll
      for (int q = 0; q < 4; ++q)
        if (v[q]) word |= (1u << (k * 4 + q));
    }
  }
  bm[t] = word;
}

// ---------------------------------------------------------------------------
// k_prep: x = node@W via bf16 MFMA (64x64 tiles). Emits XT (bf16 [256][4096],
// coalesced via LDS transpose), sSrcT/sTgtT ([8][4096], log2-domain).
// ---------------------------------------------------------------------------
__global__ __launch_bounds__(256) void k_prep(
    const float* __restrict__ node, const float* __restrict__ Wm,
    const float* __restrict__ avec, uint16_t* __restrict__ XT,
    float* __restrict__ sSrcT, float* __restrict__ sTgtT) {
  __shared__ __bf16 Ald[64][40];
  __shared__ __bf16 Bld[64][40];
  __shared__ __bf16 Cs[64][72];
  const int tid = threadIdx.x;
  const int wv = tid >> 6, ln = tid & 63, nl = ln & 15, qd = ln >> 4;
  const int row0 = blockIdx.x * 64, col0 = blockIdx.y * 64;
  const int rA = tid >> 2, kA = (tid & 3) * 8;
  const int kB = tid >> 3, cB = (tid & 7) * 8;

  f32x4 acc[4] = {{0,0,0,0},{0,0,0,0},{0,0,0,0},{0,0,0,0}};
  float4 a0, a1, b0, b1;

  auto ldg = [&](int k0) {
    a0 = *(const float4*)(node + (size_t)(row0 + rA) * KIN + k0 + kA);
    a1 = *(const float4*)(node + (size_t)(row0 + rA) * KIN + k0 + kA + 4);
    b0 = *(const float4*)(Wm + (size_t)(k0 + kB) * HF + col0 + cB);
    b1 = *(const float4*)(Wm + (size_t)(k0 + kB) * HF + col0 + cB + 4);
  };

  ldg(0);
  for (int k0 = 0; k0 < KIN; k0 += 32) {
    __syncthreads();
    {
      union { bf16x8 v; s16x8 s; } pk;
      pk.v[0] = (__bf16)a0.x; pk.v[1] = (__bf16)a0.y;
      pk.v[2] = (__bf16)a0.z; pk.v[3] = (__bf16)a0.w;
      pk.v[4] = (__bf16)a1.x; pk.v[5] = (__bf16)a1.y;
      pk.v[6] = (__bf16)a1.z; pk.v[7] = (__bf16)a1.w;
      *(s16x8*)&Ald[rA][kA] = pk.s;
      Bld[cB + 0][kB] = (__bf16)b0.x;
      Bld[cB + 1][kB] = (__bf16)b0.y;
      Bld[cB + 2][kB] = (__bf16)b0.z;
      Bld[cB + 3][kB] = (__bf16)b0.w;
      Bld[cB + 4][kB] = (__bf16)b1.x;
      Bld[cB + 5][kB] = (__bf16)b1.y;
      Bld[cB + 6][kB] = (__bf16)b1.z;
      Bld[cB + 7][kB] = (__bf16)b1.w;
    }
    __syncthreads();
    if (k0 + 32 < KIN) ldg(k0 + 32);
    const s16x8 af = *(const s16x8*)&Ald[wv * 16 + nl][qd * 8];
#pragma unroll
    for (int ct = 0; ct < 4; ++ct) {
      const s16x8 bfr = *(const s16x8*)&Bld[ct * 16 + nl][qd * 8];
      acc[ct] = __builtin_amdgcn_mfma_f32_16x16x32_bf16(af, bfr, acc[ct], 0, 0, 0);
    }
  }

#pragma unroll
  for (int ct = 0; ct < 4; ++ct)
#pragma unroll
    for (int r = 0; r < 4; ++r)
      Cs[ct * 16 + nl][wv * 16 + qd * 4 + r] = (__bf16)acc[ct][r];
  __syncthreads();
  {
    const int xr = tid >> 2;
#pragma unroll
    for (int sseg = 0; sseg < 2; ++sseg) {
      const int sc = ((tid & 3) * 2 + sseg) * 8;
      *(s16x8*)(XT + (size_t)(col0 + xr) * NN + row0 + sc) =
          *(const s16x8*)&Cs[xr][sc];
    }
  }

  const float as0 = avec[nl] * LOG2E, as1 = avec[16 + nl] * LOG2E;
  const float at0 = avec[32 + nl] * LOG2E, at1 = avec[48 + nl] * LOG2E;
#pragma unroll
  for (int hp = 0; hp < 2; ++hp) {
    float ps[4], pt[4];
#pragma unroll
    for (int r = 0; r < 4; ++r) {
      ps[r] = acc[2 * hp][r] * as0 + acc[2 * hp + 1][r] * as1;
      pt[r] = acc[2 * hp][r] * at0 + acc[2 * hp + 1][r] * at1;
    }
#pragma unroll
    for (int m = 1; m <= 8; m <<= 1)
#pragma unroll
      for (int r = 0; r < 4; ++r) {
        ps[r] += __shfl_xor(ps[r], m);
        pt[r] += __shfl_xor(pt[r], m);
      }
    if (nl == 0) {
      const int h = blockIdx.y * 2 + hp;
#pragma unroll
      for (int r = 0; r < 4; ++r) {
        sSrcT[h * NN + row0 + wv * 16 + qd * 4 + r] = ps[r];
        sTgtT[h * NN + row0 + wv * 16 + qd * 4 + r] = pt[r];
      }
    }
  }
}

// ---------------------------------------------------------------------------
// k_attn: one wave per (16-row tile, head, j-slice). No LDS, no barriers.
// Adjacency from the 2 MB bitmask (L2-resident): per 128-j chunk one u32x4
// per lane (dword st = 32 j's of step st; byte qd = this quad's octet).
// Mask applied per-element via cndmask on the float p. den via ones-MFMA.
// ---------------------------------------------------------------------------
__global__ __launch_bounds__(256) void k_attn(
    const uint32_t* __restrict__ bm, const uint16_t* __restrict__ XT,
    const float* __restrict__ sSrcT, const float* __restrict__ sTgtT,
    uint16_t* __restrict__ pnum, float* __restrict__ pden,
    float* __restrict__ out) {
  const int tid = threadIdx.x;
  const int wv = tid >> 6, ln = tid & 63, nl = ln & 15, qd = ln >> 4;
  const int tile = blockIdx.x >> 1;                 // 0..255 (16-row tiles)
  const int h = (blockIdx.x & 1) * 4 + wv;          // 0..7
  const int js = blockIdx.y, JS = gridDim.y;
  const int i0 = tile * 16;
  const int jlen = NN / JS, j0 = js * jlen, NC = jlen / 128;

  const float tl = sTgtT[h * NN + i0 + nl];
  const float* sS = sSrcT + h * NN;
  const uint16_t* x0 = XT + (size_t)(h * 32 + nl) * NN;
  const uint16_t* x1 = x0 + (size_t)16 * NN;
  const uint32_t* rowbm = bm + (size_t)(i0 + nl) * 128;

  const short one_bf = (short)0x3F80;
  const s16x8 ONES = {one_bf, one_bf, one_bf, one_bf,
                      one_bf, one_bf, one_bf, one_bf};

  f32x4 acc0 = {0,0,0,0}, acc1 = {0,0,0,0}, accD = {0,0,0,0};

  u32x4 bits = *(const u32x4*)(rowbm + (j0 >> 5));
  for (int c = 0; c < NC; ++c) {
    const int jb = j0 + c * 128;
    u32x4 nbits;
    if (c + 1 < NC) nbits = *(const u32x4*)(rowbm + ((jb + 128) >> 5));
#pragma unroll
    for (int st = 0; st < 4; ++st) {
      const int jq = jb + st * 32 + qd * 8;
      const uint32_t bytev = (bits[st] >> (qd * 8)) & 0xFFu;
      const s16x8 bx0 = *(const s16x8*)(x0 + jq);
      const s16x8 bx1 = *(const s16x8*)(x1 + jq);
      const f32x4 s0 = *(const f32x4*)(sS + jq);
      const f32x4 s1 = *(const f32x4*)(sS + jq + 4);
      const float sv[8] = {s0[0], s0[1], s0[2], s0[3],
                           s1[0], s1[1], s1[2], s1[3]};
      union { bf16x8 b; s16x8 s; } af;
#pragma unroll
      for (int cc = 0; cc < 8; ++cc) {
        const float v = tl + sv[cc];
        const float w = fmaxf(v, 0.2f * v);
        const float p = (bytev & (1u << cc)) ? EXP2(w) : 0.0f;
        af.b[cc] = (__bf16)p;
      }
      acc0 = __builtin_amdgcn_mfma_f32_16x16x32_bf16(af.s, bx0, acc0, 0, 0, 0);
      acc1 = __builtin_amdgcn_mfma_f32_16x16x32_bf16(af.s, bx1, acc1, 0, 0, 0);
      accD = __builtin_amdgcn_mfma_f32_16x16x32_bf16(af.s, ONES, accD, 0, 0, 0);
    }
    bits = nbits;
  }

  if (JS == 1) {
#pragma unroll
    for (int r = 0; r < 4; ++r) {
      const int rw = qd * 4 + r;
      const float inv = 1.0f / accD[r];
      out[(size_t)(i0 + rw) * HF + h * 32 + nl] = acc0[r] * inv;
      out[(size_t)(i0 + rw) * HF + h * 32 + 16 + nl] = acc1[r] * inv;
    }
  } else {
    union { __bf16 b; uint16_t u; } cv;
    const size_t pb = (((size_t)js * 256 + tile) * HH + h) * 2;
#pragma unroll
    for (int r = 0; r < 4; ++r) {
      const int rw = qd * 4 + r;
      cv.b = (__bf16)acc0[r];
      pnum[(pb * 16 + rw) * 16 + nl] = cv.u;
      cv.b = (__bf16)acc1[r];
      pnum[((pb + 1) * 16 + rw) * 16 + nl] = cv.u;
    }
    if (nl == 0) {
#pragma unroll
      for (int r = 0; r < 4; ++r)
        pden[((size_t)js * 256 + tile) * 128 + h * 16 + qd * 4 + r] = accD[r];
    }
  }
}

// ---------------------------------------------------------------------------
__global__ __launch_bounds__(256) void k_reduce(
    const uint16_t* __restrict__ pnum, const float* __restrict__ pden,
    float* __restrict__ out, int JS) {
  const int gid = blockIdx.x * 256 + threadIdx.x;
  const int i = gid >> 8, col = gid & 255;
  const int tile = i >> 4, r = i & 15;
  const int h = col >> 5, ct = (col >> 4) & 1, cc = col & 15;
  float num = 0.f, den = 0.f;
  for (int js = 0; js < JS; ++js) {
    union { uint16_t u; __bf16 b; } cv;
    cv.u = pnum[(((((size_t)js * 256 + tile) * 8 + h) * 2 + ct) * 16 + r) * 16 + cc];
    num += (float)cv.b;
    den += pden[((size_t)js * 256 + tile) * 128 + h * 16 + r];
  }
  out[gid] = num / den;
}

// ---------------------------------------------------------------------------
extern "C" void kernel_launch(void* const* d_in, const int* in_sizes, int n_in,
                              void* d_out, int out_size, void* d_ws, size_t ws_size,
                              hipStream_t stream) {
  const float* node = (const float*)d_in[0];
  const void* adj = d_in[1];
  const float* Wm = (const float*)d_in[2];
  const float* avec = (const float*)d_in[3];
  float* out = (float*)d_out;

  uint8_t* ws = (uint8_t*)d_ws;
  uint16_t* XT = (uint16_t*)ws;                        // 2 MB
  float* sSrcT = (float*)(ws + 0x200000);              // 128 KB
  float* sTgtT = (float*)(ws + 0x220000);              // 128 KB
  uint32_t* bm = (uint32_t*)(ws + 0x240000);           // 2 MB bitmask
  const size_t base = 0x440000;
  const size_t per = 2097152ull + 131072ull;           // pnum + pden per slice
  int JS = 1;
  if (ws_size >= base + 8 * per) JS = 8;
  else if (ws_size >= base + 4 * per) JS = 4;
  else if (ws_size >= base + 2 * per) JS = 2;
  uint16_t* pnum = (uint16_t*)(ws + base);
  float* pden = (float*)(ws + base + (size_t)JS * 2097152ull);

  hipLaunchKernelGGL(k_pack, dim3(2048), dim3(256), 0, stream, adj, bm);
  hipLaunchKernelGGL(k_prep, dim3(64, 4), dim3(256), 0, stream,
                     node, Wm, avec, XT, sSrcT, sTgtT);
  hipLaunchKernelGGL(k_attn, dim3(512, JS), dim3(256), 0, stream,
                     bm, XT, sSrcT, sTgtT, pnum, pden, out);
  if (JS > 1)
    hipLaunchKernelGGL(k_reduce, dim3(4096), dim3(256), 0, stream,
                       pnum, pden, out, JS);
}

// Round 8
// 186.177 us; speedup vs baseline: 1.2742x; 1.2742x over previous
//
#include <hip/hip_runtime.h>
#include <hip/hip_bf16.h>
#include <stdint.h>

#define NN 4096
#define KIN 512
#define HH 8
#define HF 256
#define LOG2E 1.4426950408889634f

typedef float f32x4 __attribute__((ext_vector_type(4)));
typedef short s16x8 __attribute__((ext_vector_type(8)));
typedef __bf16 bf16x8 __attribute__((ext_vector_type(8)));
typedef unsigned int u32x4 __attribute__((ext_vector_type(4)));

#if defined(__has_builtin)
#if __has_builtin(__builtin_amdgcn_exp2f)
#define EXP2(x) __builtin_amdgcn_exp2f(x)
#else
#define EXP2(x) exp2f(x)
#endif
#else
#define EXP2(x) exp2f(x)
#endif

// ---------------------------------------------------------------------------
// k_pack: adjacency (storage mode sniffed per-block) -> bitmask bm[4096][128]
// u32 (2 MB). One HBM-rate pass.
// ---------------------------------------------------------------------------
__global__ __launch_bounds__(256) void k_pack(const void* __restrict__ adjv,
                                              uint32_t* __restrict__ bm) {
  __shared__ int smode;
  if (threadIdx.x == 0) {
    const uint32_t* aw = (const uint32_t*)adjv;
    const uint32_t w0 = aw[0];
    int f;
    if (w0 == 0x3F800000u) f = 2;                 // fp32 0/1
    else if ((w0 & 0xFFFFu) == 0x3F80u) f = 3;    // bf16 0/1
    else {
      int alli = 1;
      for (int k = 0; k < 64; ++k)
        if (aw[k] > 1u) { alli = 0; break; }
      f = alli ? 1 : 0;                           // int32 : uint8
    }
    smode = f;
  }
  __syncthreads();
  const int mode = smode;
  const int t = blockIdx.x * 256 + threadIdx.x;   // 0..524287
  const int r = t >> 7, w = t & 127;              // row, 32-elem word
  uint32_t word = 0;
  if (mode == 0) {
    const u32x4* p = (const u32x4*)((const uint8_t*)adjv + ((size_t)r << 12) + w * 32);
#pragma unroll
    for (int k = 0; k < 2; ++k) {
      const u32x4 v = __builtin_nontemporal_load(&p[k]);
#pragma unroll
      for (int q = 0; q < 4; ++q)
#pragma unroll
        for (int b = 0; b < 4; ++b)
          if ((v[q] >> (8 * b)) & 0xFFu) word |= (1u << (k * 16 + q * 4 + b));
    }
  } else if (mode == 3) {
    const u32x4* p = (const u32x4*)((const uint16_t*)adjv + ((size_t)r << 12) + w * 32);
#pragma unroll
    for (int k = 0; k < 4; ++k) {
      const u32x4 v = __builtin_nontemporal_load(&p[k]);
#pragma unroll
      for (int q = 0; q < 4; ++q) {
        if (v[q] & 0xFFFFu) word |= (1u << (k * 8 + q * 2 + 0));
        if (v[q] >> 16)     word |= (1u << (k * 8 + q * 2 + 1));
      }
    }
  } else {
    const u32x4* p = (const u32x4*)((const uint32_t*)adjv + ((size_t)r << 12) + w * 32);
#pragma unroll
    for (int k = 0; k < 8; ++k) {
      const u32x4 v = __builtin_nontemporal_load(&p[k]);
#pragma unroll
      for (int q = 0; q < 4; ++q)
        if (v[q]) word |= (1u << (k * 4 + q));
    }
  }
  bm[t] = word;
}

// ---------------------------------------------------------------------------
// k_prep: x = node@W via bf16 MFMA (64x64 tiles). Emits XB in B-FRAGMENT-
// MAJOR layout: XB[h][jc][half][lane][8] bf16 (2 MB) — so k_attn's B-frag
// load is one contiguous 1KB block per wave. Also sSrcT/sTgtT (log2-domain).
// ---------------------------------------------------------------------------
__global__ __launch_bounds__(256) void k_prep(
    const float* __restrict__ node, const float* __restrict__ Wm,
    const float* __restrict__ avec, uint16_t* __restrict__ XB,
    float* __restrict__ sSrcT, float* __restrict__ sTgtT) {
  __shared__ __bf16 Ald[64][40];
  __shared__ __bf16 Bld[64][40];
  __shared__ __bf16 Cs[64][72];
  const int tid = threadIdx.x;
  const int wv = tid >> 6, ln = tid & 63, nl = ln & 15, qd = ln >> 4;
  const int row0 = blockIdx.x * 64, col0 = blockIdx.y * 64;
  const int rA = tid >> 2, kA = (tid & 3) * 8;
  const int kB = tid >> 3, cB = (tid & 7) * 8;

  f32x4 acc[4] = {{0,0,0,0},{0,0,0,0},{0,0,0,0},{0,0,0,0}};
  float4 a0, a1, b0, b1;

  auto ldg = [&](int k0) {
    a0 = *(const float4*)(node + (size_t)(row0 + rA) * KIN + k0 + kA);
    a1 = *(const float4*)(node + (size_t)(row0 + rA) * KIN + k0 + kA + 4);
    b0 = *(const float4*)(Wm + (size_t)(k0 + kB) * HF + col0 + cB);
    b1 = *(const float4*)(Wm + (size_t)(k0 + kB) * HF + col0 + cB + 4);
  };

  ldg(0);
  for (int k0 = 0; k0 < KIN; k0 += 32) {
    __syncthreads();
    {
      union { bf16x8 v; s16x8 s; } pk;
      pk.v[0] = (__bf16)a0.x; pk.v[1] = (__bf16)a0.y;
      pk.v[2] = (__bf16)a0.z; pk.v[3] = (__bf16)a0.w;
      pk.v[4] = (__bf16)a1.x; pk.v[5] = (__bf16)a1.y;
      pk.v[6] = (__bf16)a1.z; pk.v[7] = (__bf16)a1.w;
      *(s16x8*)&Ald[rA][kA] = pk.s;
      Bld[cB + 0][kB] = (__bf16)b0.x;
      Bld[cB + 1][kB] = (__bf16)b0.y;
      Bld[cB + 2][kB] = (__bf16)b0.z;
      Bld[cB + 3][kB] = (__bf16)b0.w;
      Bld[cB + 4][kB] = (__bf16)b1.x;
      Bld[cB + 5][kB] = (__bf16)b1.y;
      Bld[cB + 6][kB] = (__bf16)b1.z;
      Bld[cB + 7][kB] = (__bf16)b1.w;
    }
    __syncthreads();
    if (k0 + 32 < KIN) ldg(k0 + 32);
    const s16x8 af = *(const s16x8*)&Ald[wv * 16 + nl][qd * 8];
#pragma unroll
    for (int ct = 0; ct < 4; ++ct) {
      const s16x8 bfr = *(const s16x8*)&Bld[ct * 16 + nl][qd * 8];
      acc[ct] = __builtin_amdgcn_mfma_f32_16x16x32_bf16(af, bfr, acc[ct], 0, 0, 0);
    }
  }

  // stage C-tile in LDS [col][row]
#pragma unroll
  for (int ct = 0; ct < 4; ++ct)
#pragma unroll
    for (int r = 0; r < 4; ++r)
      Cs[ct * 16 + nl][wv * 16 + qd * 4 + r] = (__bf16)acc[ct][r];
  __syncthreads();
  // write XB: 8 combos (hp, jcl, half) x 64 lanes, 16B each, coalesced
  {
    const int l = tid & 63;
#pragma unroll
    for (int i = 0; i < 2; ++i) {
      const int cmb = i * 4 + (tid >> 6);
      const int hp = cmb >> 2, jcl = (cmb >> 1) & 1, half = cmb & 1;
      const int cp = hp * 32 + half * 16 + (l & 15);
      const int rp = jcl * 32 + (l >> 4) * 8;
      const int hg = blockIdx.y * 2 + hp;
      const int jc = blockIdx.x * 2 + jcl;
      *(s16x8*)(XB + (((size_t)(hg * 128 + jc)) * 2 + half) * 512 + l * 8) =
          *(const s16x8*)&Cs[cp][rp];
    }
  }

  const float as0 = avec[nl] * LOG2E, as1 = avec[16 + nl] * LOG2E;
  const float at0 = avec[32 + nl] * LOG2E, at1 = avec[48 + nl] * LOG2E;
#pragma unroll
  for (int hp = 0; hp < 2; ++hp) {
    float ps[4], pt[4];
#pragma unroll
    for (int r = 0; r < 4; ++r) {
      ps[r] = acc[2 * hp][r] * as0 + acc[2 * hp + 1][r] * as1;
      pt[r] = acc[2 * hp][r] * at0 + acc[2 * hp + 1][r] * at1;
    }
#pragma unroll
    for (int m = 1; m <= 8; m <<= 1)
#pragma unroll
      for (int r = 0; r < 4; ++r) {
        ps[r] += __shfl_xor(ps[r], m);
        pt[r] += __shfl_xor(pt[r], m);
      }
    if (nl == 0) {
      const int h = blockIdx.y * 2 + hp;
#pragma unroll
      for (int r = 0; r < 4; ++r) {
        sSrcT[h * NN + row0 + wv * 16 + qd * 4 + r] = ps[r];
        sTgtT[h * NN + row0 + wv * 16 + qd * 4 + r] = pt[r];
      }
    }
  }
}

// ---------------------------------------------------------------------------
// k_attn: block = (16-row tile, head), 4 waves each owning a 1024-j slice.
// B-frags are contiguous 1KB loads from XB; adjacency from L2-resident
// bitmask; den via ones-MFMA. Cross-wave reduction in LDS; wave 0 writes out.
// ---------------------------------------------------------------------------
__global__ __launch_bounds__(256, 8) void k_attn(
    const uint32_t* __restrict__ bm, const uint16_t* __restrict__ XB,
    const float* __restrict__ sSrcT, const float* __restrict__ sTgtT,
    float* __restrict__ out) {
  __shared__ float Red[3][64][13];
  const int tid = threadIdx.x;
  const int wv = tid >> 6, ln = tid & 63, nl = ln & 15, qd = ln >> 4;
  const int tile = blockIdx.x >> 3;          // 0..255
  const int h = blockIdx.x & 7;
  const int i0 = tile * 16;
  const int j0 = wv * 1024;

  const float tl = sTgtT[h * NN + i0 + nl];
  const float* sS = sSrcT + h * NN;
  const uint16_t* xb = XB + ((size_t)h << 17) + ln * 8;
  const uint32_t* rowbm = bm + (size_t)(i0 + nl) * 128;

  const short one_bf = (short)0x3F80;
  const s16x8 ONES = {one_bf, one_bf, one_bf, one_bf,
                      one_bf, one_bf, one_bf, one_bf};

  f32x4 acc0 = {0,0,0,0}, acc1 = {0,0,0,0}, accD = {0,0,0,0};

  u32x4 bits = *(const u32x4*)(rowbm + (j0 >> 5));
  for (int c = 0; c < 8; ++c) {
    const int jb = j0 + c * 128;
    u32x4 nbits;
    if (c + 1 < 8) nbits = *(const u32x4*)(rowbm + ((jb + 128) >> 5));
#pragma unroll
    for (int st = 0; st < 4; ++st) {
      const int jq = jb + st * 32;           // 32-j chunk base
      const int jc = jq >> 5;
      const s16x8 bx0 = *(const s16x8*)(xb + (size_t)jc * 1024);
      const s16x8 bx1 = *(const s16x8*)(xb + (size_t)jc * 1024 + 512);
      const f32x4 s0 = *(const f32x4*)(sS + jq + qd * 8);
      const f32x4 s1 = *(const f32x4*)(sS + jq + qd * 8 + 4);
      const uint32_t bytev = (bits[st] >> (qd * 8)) & 0xFFu;
      const float sv[8] = {s0[0], s0[1], s0[2], s0[3],
                           s1[0], s1[1], s1[2], s1[3]};
      union { bf16x8 b; s16x8 s; } af;
#pragma unroll
      for (int cc = 0; cc < 8; ++cc) {
        const float v = tl + sv[cc];
        const float w = fmaxf(v, 0.2f * v);
        const float p = (bytev & (1u << cc)) ? EXP2(w) : 0.0f;
        af.b[cc] = (__bf16)p;
      }
      acc0 = __builtin_amdgcn_mfma_f32_16x16x32_bf16(af.s, bx0, acc0, 0, 0, 0);
      acc1 = __builtin_amdgcn_mfma_f32_16x16x32_bf16(af.s, bx1, acc1, 0, 0, 0);
      accD = __builtin_amdgcn_mfma_f32_16x16x32_bf16(af.s, ONES, accD, 0, 0, 0);
    }
    bits = nbits;
  }

  // cross-wave reduction: waves 1..3 dump, wave 0 sums + writes out
  if (wv > 0) {
#pragma unroll
    for (int r = 0; r < 4; ++r) {
      Red[wv - 1][ln][r] = acc0[r];
      Red[wv - 1][ln][4 + r] = acc1[r];
      Red[wv - 1][ln][8 + r] = accD[r];
    }
  }
  __syncthreads();
  if (wv == 0) {
#pragma unroll
    for (int w = 0; w < 3; ++w)
#pragma unroll
      for (int r = 0; r < 4; ++r) {
        acc0[r] += Red[w][ln][r];
        acc1[r] += Red[w][ln][4 + r];
        accD[r] += Red[w][ln][8 + r];
      }
#pragma unroll
    for (int r = 0; r < 4; ++r) {
      const int rw = qd * 4 + r;
      const float inv = 1.0f / accD[r];
      out[(size_t)(i0 + rw) * HF + h * 32 + nl] = acc0[r] * inv;
      out[(size_t)(i0 + rw) * HF + h * 32 + 16 + nl] = acc1[r] * inv;
    }
  }
}

// ---------------------------------------------------------------------------
extern "C" void kernel_launch(void* const* d_in, const int* in_sizes, int n_in,
                              void* d_out, int out_size, void* d_ws, size_t ws_size,
                              hipStream_t stream) {
  const float* node = (const float*)d_in[0];
  const void* adj = d_in[1];
  const float* Wm = (const float*)d_in[2];
  const float* avec = (const float*)d_in[3];
  float* out = (float*)d_out;

  uint8_t* ws = (uint8_t*)d_ws;
  uint16_t* XB = (uint16_t*)ws;                        // 2 MB (frag-major X)
  float* sSrcT = (float*)(ws + 0x200000);              // 128 KB
  float* sTgtT = (float*)(ws + 0x220000);              // 128 KB
  uint32_t* bm = (uint32_t*)(ws + 0x240000);           // 2 MB bitmask

  hipLaunchKernelGGL(k_pack, dim3(2048), dim3(256), 0, stream, adj, bm);
  hipLaunchKernelGGL(k_prep, dim3(64, 4), dim3(256), 0, stream,
                     node, Wm, avec, XB, sSrcT, sTgtT);
  hipLaunchKernelGGL(k_attn, dim3(2048), dim3(256), 0, stream,
                     bm, XB, sSrcT, sTgtT, out);
}

// Round 9
// 175.965 us; speedup vs baseline: 1.3481x; 1.0580x over previous
//
#include <hip/hip_runtime.h>
#include <hip/hip_bf16.h>
#include <stdint.h>

#define NN 4096
#define KIN 512
#define HH 8
#define HF 256
#define LOG2E 1.4426950408889634f

typedef float f32x4 __attribute__((ext_vector_type(4)));
typedef short s16x8 __attribute__((ext_vector_type(8)));
typedef short s16x2 __attribute__((ext_vector_type(2)));
typedef __bf16 bf16x8 __attribute__((ext_vector_type(8)));
typedef _Float16 h16x8 __attribute__((ext_vector_type(8)));
typedef unsigned int u32x4 __attribute__((ext_vector_type(4)));

extern "C" __device__ _Float16 __ocml_exp2_f16(_Float16);

// ---------------------------------------------------------------------------
// k_pack: adjacency (storage mode sniffed per-block) -> bitmask bm[4096][128]
// u32 (2 MB). One HBM-rate pass.
// ---------------------------------------------------------------------------
__global__ __launch_bounds__(256) void k_pack(const void* __restrict__ adjv,
                                              uint32_t* __restrict__ bm) {
  __shared__ int smode;
  if (threadIdx.x == 0) {
    const uint32_t* aw = (const uint32_t*)adjv;
    const uint32_t w0 = aw[0];
    int f;
    if (w0 == 0x3F800000u) f = 2;                 // fp32 0/1
    else if ((w0 & 0xFFFFu) == 0x3F80u) f = 3;    // bf16 0/1
    else {
      int alli = 1;
      for (int k = 0; k < 64; ++k)
        if (aw[k] > 1u) { alli = 0; break; }
      f = alli ? 1 : 0;                           // int32 : uint8
    }
    smode = f;
  }
  __syncthreads();
  const int mode = smode;
  const int t = blockIdx.x * 256 + threadIdx.x;   // 0..524287
  const int r = t >> 7, w = t & 127;              // row, 32-elem word
  uint32_t word = 0;
  if (mode == 0) {
    const u32x4* p = (const u32x4*)((const uint8_t*)adjv + ((size_t)r << 12) + w * 32);
#pragma unroll
    for (int k = 0; k < 2; ++k) {
      const u32x4 v = __builtin_nontemporal_load(&p[k]);
#pragma unroll
      for (int q = 0; q < 4; ++q)
#pragma unroll
        for (int b = 0; b < 4; ++b)
          if ((v[q] >> (8 * b)) & 0xFFu) word |= (1u << (k * 16 + q * 4 + b));
    }
  } else if (mode == 3) {
    const u32x4* p = (const u32x4*)((const uint16_t*)adjv + ((size_t)r << 12) + w * 32);
#pragma unroll
    for (int k = 0; k < 4; ++k) {
      const u32x4 v = __builtin_nontemporal_load(&p[k]);
#pragma unroll
      for (int q = 0; q < 4; ++q) {
        if (v[q] & 0xFFFFu) word |= (1u << (k * 8 + q * 2 + 0));
        if (v[q] >> 16)     word |= (1u << (k * 8 + q * 2 + 1));
      }
    }
  } else {
    const u32x4* p = (const u32x4*)((const uint32_t*)adjv + ((size_t)r << 12) + w * 32);
#pragma unroll
    for (int k = 0; k < 8; ++k) {
      const u32x4 v = __builtin_nontemporal_load(&p[k]);
#pragma unroll
      for (int q = 0; q < 4; ++q)
        if (v[q]) word |= (1u << (k * 4 + q));
    }
  }
  bm[t] = word;
}

// ---------------------------------------------------------------------------
// k_prep: x = node@W via bf16 MFMA (64x64 tiles). Emits XB in B-FRAGMENT-
// MAJOR layout as f16: XB[h][jc][half][lane][8] (2 MB), plus sSrcT/sTgtT
// ([8][4096] f16, log2-domain).
// ---------------------------------------------------------------------------
__global__ __launch_bounds__(256) void k_prep(
    const float* __restrict__ node, const float* __restrict__ Wm,
    const float* __restrict__ avec, _Float16* __restrict__ XB,
    _Float16* __restrict__ sSrcT, _Float16* __restrict__ sTgtT) {
  __shared__ __bf16 Ald[64][40];
  __shared__ __bf16 Bld[64][40];
  __shared__ _Float16 Cs[64][72];
  const int tid = threadIdx.x;
  const int wv = tid >> 6, ln = tid & 63, nl = ln & 15, qd = ln >> 4;
  const int row0 = blockIdx.x * 64, col0 = blockIdx.y * 64;
  const int rA = tid >> 2, kA = (tid & 3) * 8;
  const int kB = tid >> 3, cB = (tid & 7) * 8;

  f32x4 acc[4] = {{0,0,0,0},{0,0,0,0},{0,0,0,0},{0,0,0,0}};
  float4 a0, a1, b0, b1;

  auto ldg = [&](int k0) {
    a0 = *(const float4*)(node + (size_t)(row0 + rA) * KIN + k0 + kA);
    a1 = *(const float4*)(node + (size_t)(row0 + rA) * KIN + k0 + kA + 4);
    b0 = *(const float4*)(Wm + (size_t)(k0 + kB) * HF + col0 + cB);
    b1 = *(const float4*)(Wm + (size_t)(k0 + kB) * HF + col0 + cB + 4);
  };

  ldg(0);
  for (int k0 = 0; k0 < KIN; k0 += 32) {
    __syncthreads();
    {
      union { bf16x8 v; s16x8 s; } pk;
      pk.v[0] = (__bf16)a0.x; pk.v[1] = (__bf16)a0.y;
      pk.v[2] = (__bf16)a0.z; pk.v[3] = (__bf16)a0.w;
      pk.v[4] = (__bf16)a1.x; pk.v[5] = (__bf16)a1.y;
      pk.v[6] = (__bf16)a1.z; pk.v[7] = (__bf16)a1.w;
      *(s16x8*)&Ald[rA][kA] = pk.s;
      Bld[cB + 0][kB] = (__bf16)b0.x;
      Bld[cB + 1][kB] = (__bf16)b0.y;
      Bld[cB + 2][kB] = (__bf16)b0.z;
      Bld[cB + 3][kB] = (__bf16)b0.w;
      Bld[cB + 4][kB] = (__bf16)b1.x;
      Bld[cB + 5][kB] = (__bf16)b1.y;
      Bld[cB + 6][kB] = (__bf16)b1.z;
      Bld[cB + 7][kB] = (__bf16)b1.w;
    }
    __syncthreads();
    if (k0 + 32 < KIN) ldg(k0 + 32);
    const s16x8 af = *(const s16x8*)&Ald[wv * 16 + nl][qd * 8];
#pragma unroll
    for (int ct = 0; ct < 4; ++ct) {
      const s16x8 bfr = *(const s16x8*)&Bld[ct * 16 + nl][qd * 8];
      acc[ct] = __builtin_amdgcn_mfma_f32_16x16x32_bf16(af, bfr, acc[ct], 0, 0, 0);
    }
  }

  // stage C-tile in LDS [col][row] as f16
#pragma unroll
  for (int ct = 0; ct < 4; ++ct)
#pragma unroll
    for (int r = 0; r < 4; ++r)
      Cs[ct * 16 + nl][wv * 16 + qd * 4 + r] = (_Float16)acc[ct][r];
  __syncthreads();
  // write XB: 8 combos (hp, jcl, half) x 64 lanes, 16B each, coalesced
  {
    const int l = tid & 63;
#pragma unroll
    for (int i = 0; i < 2; ++i) {
      const int cmb = i * 4 + (tid >> 6);
      const int hp = cmb >> 2, jcl = (cmb >> 1) & 1, half = cmb & 1;
      const int cp = hp * 32 + half * 16 + (l & 15);
      const int rp = jcl * 32 + (l >> 4) * 8;
      const int hg = blockIdx.y * 2 + hp;
      const int jc = blockIdx.x * 2 + jcl;
      *(h16x8*)(XB + (((size_t)(hg * 128 + jc)) * 2 + half) * 512 + l * 8) =
          *(const h16x8*)&Cs[cp][rp];
    }
  }

  const float as0 = avec[nl] * LOG2E, as1 = avec[16 + nl] * LOG2E;
  const float at0 = avec[32 + nl] * LOG2E, at1 = avec[48 + nl] * LOG2E;
#pragma unroll
  for (int hp = 0; hp < 2; ++hp) {
    float ps[4], pt[4];
#pragma unroll
    for (int r = 0; r < 4; ++r) {
      ps[r] = acc[2 * hp][r] * as0 + acc[2 * hp + 1][r] * as1;
      pt[r] = acc[2 * hp][r] * at0 + acc[2 * hp + 1][r] * at1;
    }
#pragma unroll
    for (int m = 1; m <= 8; m <<= 1)
#pragma unroll
      for (int r = 0; r < 4; ++r) {
        ps[r] += __shfl_xor(ps[r], m);
        pt[r] += __shfl_xor(pt[r], m);
      }
    if (nl == 0) {
      const int h = blockIdx.y * 2 + hp;
#pragma unroll
      for (int r = 0; r < 4; ++r) {
        sSrcT[h * NN + row0 + wv * 16 + qd * 4 + r] = (_Float16)ps[r];
        sTgtT[h * NN + row0 + wv * 16 + qd * 4 + r] = (_Float16)pt[r];
      }
    }
  }
}

// ---------------------------------------------------------------------------
// k_attn: block = (16-row tile, head), 4 waves each owning a 1024-j slice.
// Packed-f16 score pipeline: v_pk_add/mul/max for tl+s and leaky-relu,
// v_exp_f16 per element, adjacency applied as bitwise AND with 0xFFFF/0
// masks built by packed-shift sign-spread. f16 MFMA (f32 accum).
// ---------------------------------------------------------------------------
__global__ __launch_bounds__(256, 8) void k_attn(
    const uint32_t* __restrict__ bm, const _Float16* __restrict__ XB,
    const _Float16* __restrict__ sSrcT, const _Float16* __restrict__ sTgtT,
    float* __restrict__ out) {
  __shared__ float Red[3][64][13];
  const int tid = threadIdx.x;
  const int wv = tid >> 6, ln = tid & 63, nl = ln & 15, qd = ln >> 4;
  const int tile = blockIdx.x >> 3;          // 0..255
  const int h = blockIdx.x & 7;
  const int i0 = tile * 16;
  const int j0 = wv * 1024;

  const _Float16 tlh = sTgtT[h * NN + i0 + nl];
  const h16x8 tl8 = {tlh, tlh, tlh, tlh, tlh, tlh, tlh, tlh};
  const h16x8 PT2 = {(_Float16)0.2f, (_Float16)0.2f, (_Float16)0.2f,
                     (_Float16)0.2f, (_Float16)0.2f, (_Float16)0.2f,
                     (_Float16)0.2f, (_Float16)0.2f};
  const h16x8 ONES = {(_Float16)1.0f, (_Float16)1.0f, (_Float16)1.0f,
                      (_Float16)1.0f, (_Float16)1.0f, (_Float16)1.0f,
                      (_Float16)1.0f, (_Float16)1.0f};
  const _Float16* sS = sSrcT + h * NN;
  const _Float16* xb = XB + ((size_t)h << 17) + ln * 8;
  const uint32_t* rowbm = bm + (size_t)(i0 + nl) * 128;

  f32x4 acc0 = {0,0,0,0}, acc1 = {0,0,0,0}, accD = {0,0,0,0};

  u32x4 bits = *(const u32x4*)(rowbm + (j0 >> 5));
  for (int c = 0; c < 8; ++c) {
    const int jb = j0 + c * 128;
    u32x4 nbits;
    if (c + 1 < 8) nbits = *(const u32x4*)(rowbm + ((jb + 128) >> 5));
#pragma unroll
    for (int st = 0; st < 4; ++st) {
      const int jq = jb + st * 32;           // 32-j chunk base
      const int jc = jq >> 5;
      const h16x8 bx0 = *(const h16x8*)(xb + (size_t)jc * 1024);
      const h16x8 bx1 = *(const h16x8*)(xb + (size_t)jc * 1024 + 512);
      const h16x8 sv = *(const h16x8*)(sS + jq + qd * 8);

      const h16x8 v = tl8 + sv;
      const h16x8 w = __builtin_elementwise_max(v, v * PT2);
      union { h16x8 h; uint32_t u[4]; } p;
#pragma unroll
      for (int cc = 0; cc < 8; ++cc) p.h[cc] = __ocml_exp2_f16(w[cc]);

      // adjacency: spread this lane's 8 bits into 4x(0xFFFF|0 per half) masks
      const uint32_t t8 = (bits[st] >> (qd * 8)) & 0xFFu;
      const uint32_t r8 = t8 | (t8 << 16);
#pragma unroll
      for (int k = 0; k < 4; ++k) {
        union { uint32_t u; s16x2 s; } m;
        m.u = r8;
        m.s = m.s << (s16x2){(short)(15 - 2 * k), (short)(14 - 2 * k)};
        m.s = m.s >> (s16x2){15, 15};        // arithmetic: 0xFFFF or 0
        p.u[k] &= m.u;
      }

      acc0 = __builtin_amdgcn_mfma_f32_16x16x32_f16(p.h, bx0, acc0, 0, 0, 0);
      acc1 = __builtin_amdgcn_mfma_f32_16x16x32_f16(p.h, bx1, acc1, 0, 0, 0);
      accD = __builtin_amdgcn_mfma_f32_16x16x32_f16(p.h, ONES, accD, 0, 0, 0);
    }
    bits = nbits;
  }

  // cross-wave reduction: waves 1..3 dump, wave 0 sums + writes out
  if (wv > 0) {
#pragma unroll
    for (int r = 0; r < 4; ++r) {
      Red[wv - 1][ln][r] = acc0[r];
      Red[wv - 1][ln][4 + r] = acc1[r];
      Red[wv - 1][ln][8 + r] = accD[r];
    }
  }
  __syncthreads();
  if (wv == 0) {
#pragma unroll
    for (int w = 0; w < 3; ++w)
#pragma unroll
      for (int r = 0; r < 4; ++r) {
        acc0[r] += Red[w][ln][r];
        acc1[r] += Red[w][ln][4 + r];
        accD[r] += Red[w][ln][8 + r];
      }
#pragma unroll
    for (int r = 0; r < 4; ++r) {
      const int rw = qd * 4 + r;
      const float inv = 1.0f / accD[r];
      out[(size_t)(i0 + rw) * HF + h * 32 + nl] = acc0[r] * inv;
      out[(size_t)(i0 + rw) * HF + h * 32 + 16 + nl] = acc1[r] * inv;
    }
  }
}

// ---------------------------------------------------------------------------
extern "C" void kernel_launch(void* const* d_in, const int* in_sizes, int n_in,
                              void* d_out, int out_size, void* d_ws, size_t ws_size,
                              hipStream_t stream) {
  const float* node = (const float*)d_in[0];
  const void* adj = d_in[1];
  const float* Wm = (const float*)d_in[2];
  const float* avec = (const float*)d_in[3];
  float* out = (float*)d_out;

  uint8_t* ws = (uint8_t*)d_ws;
  _Float16* XB = (_Float16*)ws;                        // 2 MB (frag-major X)
  _Float16* sSrcT = (_Float16*)(ws + 0x200000);        // 64 KB
  _Float16* sTgtT = (_Float16*)(ws + 0x210000);        // 64 KB
  uint32_t* bm = (uint32_t*)(ws + 0x240000);           // 2 MB bitmask

  hipLaunchKernelGGL(k_pack, dim3(2048), dim3(256), 0, stream, adj, bm);
  hipLaunchKernelGGL(k_prep, dim3(64, 4), dim3(256), 0, stream,
                     node, Wm, avec, XB, sSrcT, sTgtT);
  hipLaunchKernelGGL(k_attn, dim3(2048), dim3(256), 0, stream,
                     bm, XB, sSrcT, sTgtT, out);
}